// Round 10
// baseline (95.458 us; speedup 1.0000x reference)
//
#include <hip/hip_runtime.h>
#include <hip/hip_bf16.h>

#define N_NODES    100000
#define N_EDGES    1600000
#define NODE_DIM   128
#define EDGE_DIM   32
#define GLOBAL_DIM 64
#define HIDDEN_DIM 256
#define N_GRAPHS   512
#define IN_DIM     224   // 128 + 32 + 64
#define ROW33      33    // 32 dims + count col; stride-33 spreads LDS banks

#define EDGE_BLKS  512                       // half-size chunks: 2 edge blocks/CU
#define EDGE_CH    (N_EDGES / EDGE_BLKS)     // 3125
#define SLOTSZ     (N_GRAPHS * ROW33)        // 16896 ints per private slot
#define GPB        2                         // graphs per finalize+MLP block

// fixed-point scale for int32 LDS accumulation (fp32 atomicAdd = CAS loop on
// HIP without -munsafe-fp-atomics — round-3/4 lesson: int atomics are native)
#define FXS   1048576.0f          // 2^20
#define FXINV (1.0f / 1048576.0f)

// ---------------- workspace layout (4-byte units); NOTHING zero-initialized ----
#define WS_NSUM   0                                  // float[512*128]
#define WS_NCNT   (WS_NSUM + N_GRAPHS * NODE_DIM)    // float[512]
#define WS_ESLOT  (WS_NCNT + N_GRAPHS)               // int[512*16896] = 34.6 MB

// ---------------- bulk: edge hist (blocks 0..511) + node sums (512..1023) ----
__global__ __launch_bounds__(1024) void bulk(const float* __restrict__ eattr,
                                             const int* __restrict__ eidx,
                                             const float* __restrict__ x,
                                             const int* __restrict__ batch,
                                             int* __restrict__ eslot,
                                             float* __restrict__ nsum,
                                             float* __restrict__ ncnt) {
    __shared__ int ssum[SLOTSZ];             // 67.6 KB (node path reuses 16 KB)
    const int t = threadIdx.x;

    if (blockIdx.x < EDGE_BLKS) {
        // ----- edge scatter-sum: 4 lanes/edge, 1-deep prefetch -----
        for (int i = t; i < SLOTSZ; i += 1024) ssum[i] = 0;
        __syncthreads();

        const float4* eattr4 = reinterpret_cast<const float4*>(eattr);
        const int p = t & 3;                 // lane within edge: 8 floats each
        const int e1 = blockIdx.x * EDGE_CH + EDGE_CH;
        int e = blockIdx.x * EDGE_CH + (t >> 2);

        int s_nxt = 0;
        float4 va_nxt = float4{0.f, 0.f, 0.f, 0.f}, vb_nxt = va_nxt;
        if (e < e1) {                        // prefetch iteration 0
            s_nxt  = batch[eidx[e]];
            va_nxt = eattr4[(size_t)e * 8 + p * 2];
            vb_nxt = eattr4[(size_t)e * 8 + p * 2 + 1];
        }

        for (; e < e1; e += 256) {
            const int s = s_nxt;
            const float4 va = va_nxt, vb = vb_nxt;
            const int en = e + 256;
            if (en < e1) {                   // issue next loads before atomics
                s_nxt  = batch[eidx[en]];
                va_nxt = eattr4[(size_t)en * 8 + p * 2];
                vb_nxt = eattr4[(size_t)en * 8 + p * 2 + 1];
            }
            const int b = s * ROW33 + p * 8;
            atomicAdd(&ssum[b + 0], __float2int_rn(va.x * FXS));
            atomicAdd(&ssum[b + 1], __float2int_rn(va.y * FXS));
            atomicAdd(&ssum[b + 2], __float2int_rn(va.z * FXS));
            atomicAdd(&ssum[b + 3], __float2int_rn(va.w * FXS));
            atomicAdd(&ssum[b + 4], __float2int_rn(vb.x * FXS));
            atomicAdd(&ssum[b + 5], __float2int_rn(vb.y * FXS));
            atomicAdd(&ssum[b + 6], __float2int_rn(vb.z * FXS));
            atomicAdd(&ssum[b + 7], __float2int_rn(vb.w * FXS));
            if (p == 0) atomicAdd(&ssum[s * ROW33 + 32], 1);
        }
        __syncthreads();

        // flush: plain coalesced stores to block-private slot (no zero, no atomics)
        int* gs = eslot + (size_t)blockIdx.x * SLOTSZ;
        for (int i = t; i < SLOTSZ; i += 1024) gs[i] = ssum[i];
    } else {
        // ----- node range-sum: one block per graph; binary-search boundaries -----
        const int g = blockIdx.x - EDGE_BLKS;
        __shared__ int sb[2];
        if (t < 2) {                         // lower_bound(batch, g + t)
            const int target = g + t;
            int lo = 0, hi = N_NODES;
            while (lo < hi) {
                const int mid = (lo + hi) >> 1;
                if (batch[mid] < target) lo = mid + 1; else hi = mid;
            }
            sb[t] = lo;
        }
        __syncthreads();
        const int s0 = sb[0], e0 = sb[1];

        const int dq = t & 31;               // float4 dim-quarter: dims 4dq..4dq+3
        const int off = t >> 5;              // row offset 0..31
        float4 a0 = float4{0.f, 0.f, 0.f, 0.f}, a1 = a0;
        int r = s0 + off;
        for (; r + 32 < e0; r += 64) {
            const float4 v0 = *reinterpret_cast<const float4*>(x + (size_t)(r     ) * NODE_DIM + dq * 4);
            const float4 v1 = *reinterpret_cast<const float4*>(x + (size_t)(r + 32) * NODE_DIM + dq * 4);
            a0.x += v0.x; a0.y += v0.y; a0.z += v0.z; a0.w += v0.w;
            a1.x += v1.x; a1.y += v1.y; a1.z += v1.z; a1.w += v1.w;
        }
        for (; r < e0; r += 32) {
            const float4 v = *reinterpret_cast<const float4*>(x + (size_t)r * NODE_DIM + dq * 4);
            a0.x += v.x; a0.y += v.y; a0.z += v.z; a0.w += v.w;
        }
        a0.x += a1.x; a0.y += a1.y; a0.z += a1.z; a0.w += a1.w;

        float4* part4 = reinterpret_cast<float4*>(ssum);   // 16 KB of ssum
        part4[t] = a0;
        __syncthreads();
        if (t < 32) {
            float4 s = float4{0.f, 0.f, 0.f, 0.f};
#pragma unroll 32
            for (int k = 0; k < 32; ++k) {
                const float4 v = part4[t + 32 * k];
                s.x += v.x; s.y += v.y; s.z += v.z; s.w += v.w;
            }
            reinterpret_cast<float4*>(nsum)[(size_t)g * 32 + t] = s;
        }
        if (t == 0) ncnt[g] = fmaxf((float)(e0 - s0), 1.f);
    }
}

// ---------------- finalize + MLP fused: GPB graphs per block ---------------
__global__ __launch_bounds__(256) void finalize_mlp(const float* __restrict__ nsum,
                                                    const float* __restrict__ ncnt,
                                                    const int* __restrict__ eslot,
                                                    const float* __restrict__ u,
                                                    const float* __restrict__ W1, const float* __restrict__ b1,
                                                    const float* __restrict__ W2, const float* __restrict__ b2,
                                                    const float* __restrict__ W3, const float* __restrict__ b3,
                                                    float* __restrict__ out) {
    const int g0 = blockIdx.x * GPB;
    const int t = threadIdx.x;
    __shared__ float fs[GPB * IN_DIM];
    __shared__ long long redll[256];
    __shared__ long long redcnt[8];
    __shared__ float h[GPB][HIDDEN_DIM];
    __shared__ float h2[GPB][HIDDEN_DIM];
    __shared__ float red[GPB][256];
    __shared__ float s_ecnt[GPB];

    // edge dim partials: col = t&63 (g = col>>5, d = col&31), part = t>>6 over 4x128 slots
    {
        const int col = t & 63, part = t >> 6;
        const int g = col >> 5, d = col & 31;
        long long s = 0;
#pragma unroll 8
        for (int sl = part * 128; sl < part * 128 + 128; ++sl)
            s += eslot[(size_t)sl * SLOTSZ + (size_t)(g0 + g) * ROW33 + d];
        redll[t] = s;
    }
    if (t < 8) {    // counts: g = t&1, part = t>>1 over 4x128 slots
        const int g = t & 1, part = t >> 1;
        long long c = 0;
#pragma unroll 8
        for (int sl = part * 128; sl < part * 128 + 128; ++sl)
            c += eslot[(size_t)sl * SLOTSZ + (size_t)(g0 + g) * ROW33 + 32];
        redcnt[t] = c;
    }
    __syncthreads();
    if (t < GPB)
        s_ecnt[t] = fmaxf((float)(redcnt[t] + redcnt[t + 2] + redcnt[t + 4] + redcnt[t + 6]), 1.f);

    {   // node means: 2 graphs x 128 dims = 256 -> one per thread
        const int g = t >> 7, d = t & 127;
        fs[g * IN_DIM + d] = nsum[(size_t)(g0 + g) * NODE_DIM + d] / ncnt[g0 + g];
    }
    __syncthreads();
    if (t < 64) {   // edge means: combine 4 partials
        const long long tot = redll[t] + redll[t + 64] + redll[t + 128] + redll[t + 192];
        const int g = t >> 5, d = t & 31;
        fs[g * IN_DIM + NODE_DIM + d] = ((float)tot * FXINV) / s_ecnt[g];
    } else if (t < 192) {  // u copy: 2 graphs x 64
        const int i = t - 64, g = i >> 6, c = i & 63;
        fs[g * IN_DIM + NODE_DIM + EDGE_DIM + c] = u[(size_t)(g0 + g) * GLOBAL_DIM + c];
    }
    __syncthreads();

    // ---- MLP ----
    float acc0, acc1;
    const float bb1 = b1[t];
    acc0 = acc1 = bb1;
    for (int k = 0; k < IN_DIM; ++k) {
        const float w = W1[k * HIDDEN_DIM + t];
        acc0 = fmaf(fs[k], w, acc0);
        acc1 = fmaf(fs[IN_DIM + k], w, acc1);
    }
    h[0][t] = fmaxf(acc0, 0.f); h[1][t] = fmaxf(acc1, 0.f);
    __syncthreads();

    const float bb2 = b2[t];
    acc0 = acc1 = bb2;
    for (int k = 0; k < HIDDEN_DIM; ++k) {
        const float w = W2[k * HIDDEN_DIM + t];
        acc0 = fmaf(h[0][k], w, acc0);
        acc1 = fmaf(h[1][k], w, acc1);
    }
    h2[0][t] = fmaxf(acc0, 0.f); h2[1][t] = fmaxf(acc1, 0.f);
    __syncthreads();

    const int c3 = t & 63, q = t >> 6;
    acc0 = acc1 = 0.f;
    for (int k = q * 64; k < q * 64 + 64; ++k) {
        const float w = W3[k * GLOBAL_DIM + c3];
        acc0 = fmaf(h2[0][k], w, acc0);
        acc1 = fmaf(h2[1][k], w, acc1);
    }
    red[0][t] = acc0; red[1][t] = acc1;
    __syncthreads();
    if (t < GPB * GLOBAL_DIM) {
        const int g = t >> 6, c = t & 63;
        out[(size_t)(g0 + g) * GLOBAL_DIM + c] = red[g][c] + red[g][c + 64] +
                                                 red[g][c + 128] + red[g][c + 192] + b3[c];
    }
}

extern "C" void kernel_launch(void* const* d_in, const int* in_sizes, int n_in,
                              void* d_out, int out_size, void* d_ws, size_t ws_size,
                              hipStream_t stream) {
    const float* x         = (const float*)d_in[0];
    const int*   edge_idx  = (const int*)d_in[1];    // [2, E]; first E = sources
    const float* edge_attr = (const float*)d_in[2];
    const float* u         = (const float*)d_in[3];
    const int*   batch     = (const int*)d_in[4];
    const float* W1 = (const float*)d_in[5];
    const float* b1 = (const float*)d_in[6];
    const float* W2 = (const float*)d_in[7];
    const float* b2 = (const float*)d_in[8];
    const float* W3 = (const float*)d_in[9];
    const float* b3 = (const float*)d_in[10];
    float* out = (float*)d_out;

    int* ws32 = (int*)d_ws;
    float* nsum  = (float*)(ws32 + WS_NSUM);
    float* ncnt  = (float*)(ws32 + WS_NCNT);
    int*   eslot = ws32 + WS_ESLOT;

    bulk<<<EDGE_BLKS + N_GRAPHS, 1024, 0, stream>>>(edge_attr, edge_idx, x, batch,
                                                    eslot, nsum, ncnt);
    finalize_mlp<<<N_GRAPHS / GPB, 256, 0, stream>>>(nsum, ncnt, eslot, u,
                                                     W1, b1, W2, b2, W3, b3, out);
}

// Round 11
// 80.705 us; speedup vs baseline: 1.1828x; 1.1828x over previous
//
#include <hip/hip_runtime.h>
#include <hip/hip_bf16.h>

#define N_NODES    100000
#define N_EDGES    1600000
#define NODE_DIM   128
#define EDGE_DIM   32
#define GLOBAL_DIM 64
#define HIDDEN_DIM 256
#define N_GRAPHS   512
#define IN_DIM     224   // 128 + 32 + 64
#define ROW33      33    // 32 dims + count col; stride-33 spreads LDS banks

#define EDGE_BLKS  256                       // 1 edge block/CU, co-resident with node
#define EDGE_CH    (N_EDGES / EDGE_BLKS)     // 6250
#define SLOTSZ     (N_GRAPHS * ROW33)        // 16896 ints per private slot
#define GPB        2                         // graphs per finalize+MLP block

// fixed-point scale for int32 LDS accumulation (fp32 atomicAdd = CAS loop on
// HIP without -munsafe-fp-atomics — round-3/4 lesson: int atomics are native)
#define FXS   1048576.0f          // 2^20
#define FXINV (1.0f / 1048576.0f)

// ---------------- workspace layout (4-byte units); NOTHING zero-initialized ----
#define WS_NSUM   0                                  // float[512*128]
#define WS_NCNT   (WS_NSUM + N_GRAPHS * NODE_DIM)    // float[512]
#define WS_ESLOT  (WS_NCNT + N_GRAPHS)               // int[256*16896] = 17.3 MB

// ---------------- bulk: edge hist (blocks 0..255) + node sums (256..767) ----
__global__ __launch_bounds__(1024) void bulk(const float* __restrict__ eattr,
                                             const int* __restrict__ eidx,
                                             const float* __restrict__ x,
                                             const int* __restrict__ batch,
                                             int* __restrict__ eslot,
                                             float* __restrict__ nsum,
                                             float* __restrict__ ncnt) {
    __shared__ int ssum[SLOTSZ];             // 67.6 KB (node path reuses 16 KB)
    const int t = threadIdx.x;

    if (blockIdx.x < EDGE_BLKS) {
        // ----- edge scatter-sum: 3-stage software pipeline -----
        // stage 2: eidx[e+256] loaded 2 iters ahead
        // stage 1: batch[idx] gather + eattr float4 issued 1 iter ahead
        // stage 0: LDS atomics consume values loaded a full iteration ago
        for (int i = t; i < SLOTSZ; i += 1024) ssum[i] = 0;
        __syncthreads();

        const float4* eattr4 = reinterpret_cast<const float4*>(eattr);
        const int p = t & 7;                 // 8 lanes per 32-float edge row
        const int e1 = blockIdx.x * EDGE_CH + EDGE_CH;
        int e = blockIdx.x * EDGE_CH + (t >> 3);

        int s_c = 0, idx_n = 0;
        float4 v_c = float4{0.f, 0.f, 0.f, 0.f};
        if (e < e1) {                        // prologue: iter 0 chain + iter 1 idx
            const int idx0 = eidx[e];
            if (e + 128 < e1) idx_n = eidx[e + 128];
            s_c = batch[idx0];
            v_c = eattr4[(size_t)e * 8 + p];
        }

        for (; e < e1; e += 128) {
            const int en = e + 128;
            int s_n = 0;
            float4 v_n = float4{0.f, 0.f, 0.f, 0.f};
            if (en < e1) {                   // stage 1: issue next gather+payload
                s_n = batch[idx_n];
                v_n = eattr4[(size_t)en * 8 + p];
            }
            const int idx_nn = (e + 256 < e1) ? eidx[e + 256] : 0;  // stage 2

            const int b = s_c * ROW33 + p * 4;   // stage 0: consume
            atomicAdd(&ssum[b + 0], __float2int_rn(v_c.x * FXS));
            atomicAdd(&ssum[b + 1], __float2int_rn(v_c.y * FXS));
            atomicAdd(&ssum[b + 2], __float2int_rn(v_c.z * FXS));
            atomicAdd(&ssum[b + 3], __float2int_rn(v_c.w * FXS));
            if (p == 0) atomicAdd(&ssum[s_c * ROW33 + 32], 1);

            s_c = s_n; v_c = v_n; idx_n = idx_nn;  // rotate
        }
        __syncthreads();

        // flush: plain coalesced stores to block-private slot (no zero, no atomics)
        int* gs = eslot + (size_t)blockIdx.x * SLOTSZ;
        for (int i = t; i < SLOTSZ; i += 1024) gs[i] = ssum[i];
    } else {
        // ----- node range-sum: one block per graph; binary-search boundaries -----
        const int g = blockIdx.x - EDGE_BLKS;
        __shared__ int sb[2];
        if (t < 2) {                         // lower_bound(batch, g + t)
            const int target = g + t;
            int lo = 0, hi = N_NODES;
            while (lo < hi) {
                const int mid = (lo + hi) >> 1;
                if (batch[mid] < target) lo = mid + 1; else hi = mid;
            }
            sb[t] = lo;
        }
        __syncthreads();
        const int s0 = sb[0], e0 = sb[1];

        const int dq = t & 31;               // float4 dim-quarter: dims 4dq..4dq+3
        const int off = t >> 5;              // row offset 0..31
        float4 a0 = float4{0.f, 0.f, 0.f, 0.f}, a1 = a0;
        int r = s0 + off;
        for (; r + 32 < e0; r += 64) {
            const float4 v0 = *reinterpret_cast<const float4*>(x + (size_t)(r     ) * NODE_DIM + dq * 4);
            const float4 v1 = *reinterpret_cast<const float4*>(x + (size_t)(r + 32) * NODE_DIM + dq * 4);
            a0.x += v0.x; a0.y += v0.y; a0.z += v0.z; a0.w += v0.w;
            a1.x += v1.x; a1.y += v1.y; a1.z += v1.z; a1.w += v1.w;
        }
        for (; r < e0; r += 32) {
            const float4 v = *reinterpret_cast<const float4*>(x + (size_t)r * NODE_DIM + dq * 4);
            a0.x += v.x; a0.y += v.y; a0.z += v.z; a0.w += v.w;
        }
        a0.x += a1.x; a0.y += a1.y; a0.z += a1.z; a0.w += a1.w;

        float4* part4 = reinterpret_cast<float4*>(ssum);   // 16 KB of ssum
        part4[t] = a0;
        __syncthreads();
        if (t < 32) {
            float4 s = float4{0.f, 0.f, 0.f, 0.f};
#pragma unroll 32
            for (int k = 0; k < 32; ++k) {
                const float4 v = part4[t + 32 * k];
                s.x += v.x; s.y += v.y; s.z += v.z; s.w += v.w;
            }
            reinterpret_cast<float4*>(nsum)[(size_t)g * 32 + t] = s;
        }
        if (t == 0) ncnt[g] = fmaxf((float)(e0 - s0), 1.f);
    }
}

// ---------------- finalize + MLP fused: GPB graphs per block ---------------
__global__ __launch_bounds__(256) void finalize_mlp(const float* __restrict__ nsum,
                                                    const float* __restrict__ ncnt,
                                                    const int* __restrict__ eslot,
                                                    const float* __restrict__ u,
                                                    const float* __restrict__ W1, const float* __restrict__ b1,
                                                    const float* __restrict__ W2, const float* __restrict__ b2,
                                                    const float* __restrict__ W3, const float* __restrict__ b3,
                                                    float* __restrict__ out) {
    const int g0 = blockIdx.x * GPB;
    const int t = threadIdx.x;
    __shared__ float fs[GPB * IN_DIM];
    __shared__ long long redll[256];
    __shared__ long long redcnt[8];
    __shared__ float h[GPB][HIDDEN_DIM];
    __shared__ float h2[GPB][HIDDEN_DIM];
    __shared__ float red[GPB][256];
    __shared__ float s_ecnt[GPB];

    // edge dim partials: col = t&63 (g = col>>5, d = col&31), part = t>>6 over 4x64 slots
    {
        const int col = t & 63, part = t >> 6;
        const int g = col >> 5, d = col & 31;
        long long s = 0;
#pragma unroll 8
        for (int sl = part * 64; sl < part * 64 + 64; ++sl)
            s += eslot[(size_t)sl * SLOTSZ + (size_t)(g0 + g) * ROW33 + d];
        redll[t] = s;
    }
    if (t < 8) {    // counts: g = t&1, part = t>>1 over 4x64 slots
        const int g = t & 1, part = t >> 1;
        long long c = 0;
#pragma unroll 8
        for (int sl = part * 64; sl < part * 64 + 64; ++sl)
            c += eslot[(size_t)sl * SLOTSZ + (size_t)(g0 + g) * ROW33 + 32];
        redcnt[t] = c;
    }
    __syncthreads();
    if (t < GPB)
        s_ecnt[t] = fmaxf((float)(redcnt[t] + redcnt[t + 2] + redcnt[t + 4] + redcnt[t + 6]), 1.f);

    {   // node means: 2 graphs x 128 dims = 256 -> one per thread
        const int g = t >> 7, d = t & 127;
        fs[g * IN_DIM + d] = nsum[(size_t)(g0 + g) * NODE_DIM + d] / ncnt[g0 + g];
    }
    __syncthreads();
    if (t < 64) {   // edge means: combine 4 partials
        const long long tot = redll[t] + redll[t + 64] + redll[t + 128] + redll[t + 192];
        const int g = t >> 5, d = t & 31;
        fs[g * IN_DIM + NODE_DIM + d] = ((float)tot * FXINV) / s_ecnt[g];
    } else if (t < 192) {  // u copy: 2 graphs x 64
        const int i = t - 64, g = i >> 6, c = i & 63;
        fs[g * IN_DIM + NODE_DIM + EDGE_DIM + c] = u[(size_t)(g0 + g) * GLOBAL_DIM + c];
    }
    __syncthreads();

    // ---- MLP ----
    float acc0, acc1;
    const float bb1 = b1[t];
    acc0 = acc1 = bb1;
    for (int k = 0; k < IN_DIM; ++k) {
        const float w = W1[k * HIDDEN_DIM + t];
        acc0 = fmaf(fs[k], w, acc0);
        acc1 = fmaf(fs[IN_DIM + k], w, acc1);
    }
    h[0][t] = fmaxf(acc0, 0.f); h[1][t] = fmaxf(acc1, 0.f);
    __syncthreads();

    const float bb2 = b2[t];
    acc0 = acc1 = bb2;
    for (int k = 0; k < HIDDEN_DIM; ++k) {
        const float w = W2[k * HIDDEN_DIM + t];
        acc0 = fmaf(h[0][k], w, acc0);
        acc1 = fmaf(h[1][k], w, acc1);
    }
    h2[0][t] = fmaxf(acc0, 0.f); h2[1][t] = fmaxf(acc1, 0.f);
    __syncthreads();

    const int c3 = t & 63, q = t >> 6;
    acc0 = acc1 = 0.f;
    for (int k = q * 64; k < q * 64 + 64; ++k) {
        const float w = W3[k * GLOBAL_DIM + c3];
        acc0 = fmaf(h2[0][k], w, acc0);
        acc1 = fmaf(h2[1][k], w, acc1);
    }
    red[0][t] = acc0; red[1][t] = acc1;
    __syncthreads();
    if (t < GPB * GLOBAL_DIM) {
        const int g = t >> 6, c = t & 63;
        out[(size_t)(g0 + g) * GLOBAL_DIM + c] = red[g][c] + red[g][c + 64] +
                                                 red[g][c + 128] + red[g][c + 192] + b3[c];
    }
}

extern "C" void kernel_launch(void* const* d_in, const int* in_sizes, int n_in,
                              void* d_out, int out_size, void* d_ws, size_t ws_size,
                              hipStream_t stream) {
    const float* x         = (const float*)d_in[0];
    const int*   edge_idx  = (const int*)d_in[1];    // [2, E]; first E = sources
    const float* edge_attr = (const float*)d_in[2];
    const float* u         = (const float*)d_in[3];
    const int*   batch     = (const int*)d_in[4];
    const float* W1 = (const float*)d_in[5];
    const float* b1 = (const float*)d_in[6];
    const float* W2 = (const float*)d_in[7];
    const float* b2 = (const float*)d_in[8];
    const float* W3 = (const float*)d_in[9];
    const float* b3 = (const float*)d_in[10];
    float* out = (float*)d_out;

    int* ws32 = (int*)d_ws;
    float* nsum  = (float*)(ws32 + WS_NSUM);
    float* ncnt  = (float*)(ws32 + WS_NCNT);
    int*   eslot = ws32 + WS_ESLOT;

    bulk<<<EDGE_BLKS + N_GRAPHS, 1024, 0, stream>>>(edge_attr, edge_idx, x, batch,
                                                    eslot, nsum, ncnt);
    finalize_mlp<<<N_GRAPHS / GPB, 256, 0, stream>>>(nsum, ncnt, eslot, u,
                                                     W1, b1, W2, b2, W3, b3, out);
}

// Round 12
// 78.115 us; speedup vs baseline: 1.2220x; 1.0332x over previous
//
#include <hip/hip_runtime.h>
#include <hip/hip_bf16.h>

#define N_NODES    100000
#define N_EDGES    1600000
#define NODE_DIM   128
#define EDGE_DIM   32
#define GLOBAL_DIM 64
#define HIDDEN_DIM 256
#define N_GRAPHS   512
#define IN_DIM     224   // 128 + 32 + 64
#define ROW33      33    // 32 dims + count col; stride-33 spreads LDS banks

#define EDGE_BLKS  256                       // 1 edge block/CU, co-resident with node
#define EDGE_CH    (N_EDGES / EDGE_BLKS)     // 6250
#define SLOTSZ     (N_GRAPHS * ROW33)        // 16896 ints per private slot
#define GPB        2                         // graphs per finalize+MLP block

// fixed-point scale for int32 LDS accumulation (fp32 atomicAdd = CAS loop on
// HIP without -munsafe-fp-atomics — round-3/4 lesson: int atomics are native)
#define FXS   1048576.0f          // 2^20
#define FXINV (1.0f / 1048576.0f)

// ---------------- workspace layout (4-byte units); NOTHING zero-initialized ----
#define WS_NSUM   0                                  // float[512*128]
#define WS_NCNT   (WS_NSUM + N_GRAPHS * NODE_DIM)    // float[512]
#define WS_ESLOT  (WS_NCNT + N_GRAPHS)               // int[256*16896] = 17.3 MB

// ---------------- bulk: edge hist (blocks 0..255) + node sums (256..767) ----
__global__ __launch_bounds__(1024) void bulk(const float* __restrict__ eattr,
                                             const int* __restrict__ eidx,
                                             const float* __restrict__ x,
                                             const int* __restrict__ batch,
                                             int* __restrict__ eslot,
                                             float* __restrict__ nsum,
                                             float* __restrict__ ncnt) {
    __shared__ int ssum[SLOTSZ];             // 67.6 KB (node path reuses 16 KB)
    const int t = threadIdx.x;

    if (blockIdx.x < EDGE_BLKS) {
        // ----- edge scatter-sum: 3-stage pipeline x 2 independent chains -----
        // chain0 = edge e, chain1 = edge e+128; step 256.
        // stage 2: eidx loaded 2 iters ahead; stage 1: batch gather + float4
        // payload 1 iter ahead; stage 0: LDS atomics consume prior loads.
        for (int i = t; i < SLOTSZ; i += 1024) ssum[i] = 0;
        __syncthreads();

        const float4* eattr4 = reinterpret_cast<const float4*>(eattr);
        const int p = t & 7;                 // 8 lanes per 32-float edge row
        const int e1 = blockIdx.x * EDGE_CH + EDGE_CH;
        int e = blockIdx.x * EDGE_CH + (t >> 3);

        int s_c0 = 0, s_c1 = 0, idx_n0 = 0, idx_n1 = 0;
        float4 v_c0 = float4{0.f, 0.f, 0.f, 0.f}, v_c1 = v_c0;
        if (e < e1) {                        // prologue
            const int i0 = eidx[e];
            const int i1 = (e + 128 < e1) ? eidx[e + 128] : 0;
            idx_n0 = (e + 256 < e1) ? eidx[e + 256] : 0;
            idx_n1 = (e + 384 < e1) ? eidx[e + 384] : 0;
            s_c0 = batch[i0];
            v_c0 = eattr4[(size_t)e * 8 + p];
            if (e + 128 < e1) { s_c1 = batch[i1]; v_c1 = eattr4[(size_t)(e + 128) * 8 + p]; }
        }

        for (; e < e1; e += 256) {
            int s_n0 = 0, s_n1 = 0;
            float4 v_n0 = float4{0.f, 0.f, 0.f, 0.f}, v_n1 = v_n0;
            if (e + 256 < e1) { s_n0 = batch[idx_n0]; v_n0 = eattr4[(size_t)(e + 256) * 8 + p]; }
            if (e + 384 < e1) { s_n1 = batch[idx_n1]; v_n1 = eattr4[(size_t)(e + 384) * 8 + p]; }
            const int inn0 = (e + 512 < e1) ? eidx[e + 512] : 0;
            const int inn1 = (e + 640 < e1) ? eidx[e + 640] : 0;

            {
                const int b = s_c0 * ROW33 + p * 4;
                atomicAdd(&ssum[b + 0], __float2int_rn(v_c0.x * FXS));
                atomicAdd(&ssum[b + 1], __float2int_rn(v_c0.y * FXS));
                atomicAdd(&ssum[b + 2], __float2int_rn(v_c0.z * FXS));
                atomicAdd(&ssum[b + 3], __float2int_rn(v_c0.w * FXS));
                if (p == 0) atomicAdd(&ssum[s_c0 * ROW33 + 32], 1);
            }
            if (e + 128 < e1) {
                const int b = s_c1 * ROW33 + p * 4;
                atomicAdd(&ssum[b + 0], __float2int_rn(v_c1.x * FXS));
                atomicAdd(&ssum[b + 1], __float2int_rn(v_c1.y * FXS));
                atomicAdd(&ssum[b + 2], __float2int_rn(v_c1.z * FXS));
                atomicAdd(&ssum[b + 3], __float2int_rn(v_c1.w * FXS));
                if (p == 0) atomicAdd(&ssum[s_c1 * ROW33 + 32], 1);
            }

            s_c0 = s_n0; v_c0 = v_n0; s_c1 = s_n1; v_c1 = v_n1;
            idx_n0 = inn0; idx_n1 = inn1;
        }
        __syncthreads();

        // flush: plain coalesced stores to block-private slot (no zero, no atomics)
        int* gs = eslot + (size_t)blockIdx.x * SLOTSZ;
        for (int i = t; i < SLOTSZ; i += 1024) gs[i] = ssum[i];
    } else {
        // ----- node range-sum: one block per graph; binary-search boundaries -----
        const int g = blockIdx.x - EDGE_BLKS;
        __shared__ int sb[2];
        if (t < 2) {                         // lower_bound(batch, g + t)
            const int target = g + t;
            int lo = 0, hi = N_NODES;
            while (lo < hi) {
                const int mid = (lo + hi) >> 1;
                if (batch[mid] < target) lo = mid + 1; else hi = mid;
            }
            sb[t] = lo;
        }
        __syncthreads();
        const int s0 = sb[0], e0 = sb[1];

        const int dq = t & 31;               // float4 dim-quarter: dims 4dq..4dq+3
        const int off = t >> 5;              // row offset 0..31
        float4 a0 = float4{0.f, 0.f, 0.f, 0.f}, a1 = a0;
        int r = s0 + off;
        for (; r + 32 < e0; r += 64) {
            const float4 v0 = *reinterpret_cast<const float4*>(x + (size_t)(r     ) * NODE_DIM + dq * 4);
            const float4 v1 = *reinterpret_cast<const float4*>(x + (size_t)(r + 32) * NODE_DIM + dq * 4);
            a0.x += v0.x; a0.y += v0.y; a0.z += v0.z; a0.w += v0.w;
            a1.x += v1.x; a1.y += v1.y; a1.z += v1.z; a1.w += v1.w;
        }
        for (; r < e0; r += 32) {
            const float4 v = *reinterpret_cast<const float4*>(x + (size_t)r * NODE_DIM + dq * 4);
            a0.x += v.x; a0.y += v.y; a0.z += v.z; a0.w += v.w;
        }
        a0.x += a1.x; a0.y += a1.y; a0.z += a1.z; a0.w += a1.w;

        float4* part4 = reinterpret_cast<float4*>(ssum);   // 16 KB of ssum
        part4[t] = a0;
        __syncthreads();
        if (t < 32) {
            float4 s = float4{0.f, 0.f, 0.f, 0.f};
#pragma unroll 32
            for (int k = 0; k < 32; ++k) {
                const float4 v = part4[t + 32 * k];
                s.x += v.x; s.y += v.y; s.z += v.z; s.w += v.w;
            }
            reinterpret_cast<float4*>(nsum)[(size_t)g * 32 + t] = s;
        }
        if (t == 0) ncnt[g] = fmaxf((float)(e0 - s0), 1.f);
    }
}

// ---------------- finalize + MLP fused: GPB graphs per block ---------------
__global__ __launch_bounds__(256) void finalize_mlp(const float* __restrict__ nsum,
                                                    const float* __restrict__ ncnt,
                                                    const int* __restrict__ eslot,
                                                    const float* __restrict__ u,
                                                    const float* __restrict__ W1, const float* __restrict__ b1,
                                                    const float* __restrict__ W2, const float* __restrict__ b2,
                                                    const float* __restrict__ W3, const float* __restrict__ b3,
                                                    float* __restrict__ out) {
    const int g0 = blockIdx.x * GPB;
    const int t = threadIdx.x;
    __shared__ float fs[GPB * IN_DIM];
    __shared__ long long redll[256];
    __shared__ long long redcnt[8];
    __shared__ float h[GPB][HIDDEN_DIM];
    __shared__ float h2[GPB][HIDDEN_DIM];
    __shared__ float red[GPB][256];
    __shared__ float s_ecnt[GPB];

    // edge dim partials: col = t&63 (g = col>>5, d = col&31), part = t>>6 over 4x64 slots
    {
        const int col = t & 63, part = t >> 6;
        const int g = col >> 5, d = col & 31;
        long long s = 0;
#pragma unroll 8
        for (int sl = part * 64; sl < part * 64 + 64; ++sl)
            s += eslot[(size_t)sl * SLOTSZ + (size_t)(g0 + g) * ROW33 + d];
        redll[t] = s;
    }
    if (t < 8) {    // counts: g = t&1, part = t>>1 over 4x64 slots
        const int g = t & 1, part = t >> 1;
        long long c = 0;
#pragma unroll 8
        for (int sl = part * 64; sl < part * 64 + 64; ++sl)
            c += eslot[(size_t)sl * SLOTSZ + (size_t)(g0 + g) * ROW33 + 32];
        redcnt[t] = c;
    }
    __syncthreads();
    if (t < GPB)
        s_ecnt[t] = fmaxf((float)(redcnt[t] + redcnt[t + 2] + redcnt[t + 4] + redcnt[t + 6]), 1.f);

    {   // node means: 2 graphs x 128 dims = 256 -> one per thread
        const int g = t >> 7, d = t & 127;
        fs[g * IN_DIM + d] = nsum[(size_t)(g0 + g) * NODE_DIM + d] / ncnt[g0 + g];
    }
    __syncthreads();
    if (t < 64) {   // edge means: combine 4 partials
        const long long tot = redll[t] + redll[t + 64] + redll[t + 128] + redll[t + 192];
        const int g = t >> 5, d = t & 31;
        fs[g * IN_DIM + NODE_DIM + d] = ((float)tot * FXINV) / s_ecnt[g];
    } else if (t < 192) {  // u copy: 2 graphs x 64
        const int i = t - 64, g = i >> 6, c = i & 63;
        fs[g * IN_DIM + NODE_DIM + EDGE_DIM + c] = u[(size_t)(g0 + g) * GLOBAL_DIM + c];
    }
    __syncthreads();

    // ---- MLP ----
    float acc0, acc1;
    const float bb1 = b1[t];
    acc0 = acc1 = bb1;
    for (int k = 0; k < IN_DIM; ++k) {
        const float w = W1[k * HIDDEN_DIM + t];
        acc0 = fmaf(fs[k], w, acc0);
        acc1 = fmaf(fs[IN_DIM + k], w, acc1);
    }
    h[0][t] = fmaxf(acc0, 0.f); h[1][t] = fmaxf(acc1, 0.f);
    __syncthreads();

    const float bb2 = b2[t];
    acc0 = acc1 = bb2;
    for (int k = 0; k < HIDDEN_DIM; ++k) {
        const float w = W2[k * HIDDEN_DIM + t];
        acc0 = fmaf(h[0][k], w, acc0);
        acc1 = fmaf(h[1][k], w, acc1);
    }
    h2[0][t] = fmaxf(acc0, 0.f); h2[1][t] = fmaxf(acc1, 0.f);
    __syncthreads();

    const int c3 = t & 63, q = t >> 6;
    acc0 = acc1 = 0.f;
    for (int k = q * 64; k < q * 64 + 64; ++k) {
        const float w = W3[k * GLOBAL_DIM + c3];
        acc0 = fmaf(h2[0][k], w, acc0);
        acc1 = fmaf(h2[1][k], w, acc1);
    }
    red[0][t] = acc0; red[1][t] = acc1;
    __syncthreads();
    if (t < GPB * GLOBAL_DIM) {
        const int g = t >> 6, c = t & 63;
        out[(size_t)(g0 + g) * GLOBAL_DIM + c] = red[g][c] + red[g][c + 64] +
                                                 red[g][c + 128] + red[g][c + 192] + b3[c];
    }
}

extern "C" void kernel_launch(void* const* d_in, const int* in_sizes, int n_in,
                              void* d_out, int out_size, void* d_ws, size_t ws_size,
                              hipStream_t stream) {
    const float* x         = (const float*)d_in[0];
    const int*   edge_idx  = (const int*)d_in[1];    // [2, E]; first E = sources
    const float* edge_attr = (const float*)d_in[2];
    const float* u         = (const float*)d_in[3];
    const int*   batch     = (const int*)d_in[4];
    const float* W1 = (const float*)d_in[5];
    const float* b1 = (const float*)d_in[6];
    const float* W2 = (const float*)d_in[7];
    const float* b2 = (const float*)d_in[8];
    const float* W3 = (const float*)d_in[9];
    const float* b3 = (const float*)d_in[10];
    float* out = (float*)d_out;

    int* ws32 = (int*)d_ws;
    float* nsum  = (float*)(ws32 + WS_NSUM);
    float* ncnt  = (float*)(ws32 + WS_NCNT);
    int*   eslot = ws32 + WS_ESLOT;

    bulk<<<EDGE_BLKS + N_GRAPHS, 1024, 0, stream>>>(edge_attr, edge_idx, x, batch,
                                                    eslot, nsum, ncnt);
    finalize_mlp<<<N_GRAPHS / GPB, 256, 0, stream>>>(nsum, ncnt, eslot, u,
                                                     W1, b1, W2, b2, W3, b3, out);
}